// Round 7
// baseline (162.452 us; speedup 1.0000x reference)
//
#include <hip/hip_runtime.h>
#include <hip/hip_bf16.h>
#include <math.h>

#define HW 128
#define NPIX (HW * HW)
#define NB 8
#define PH 130
#define PPIX (PH * PH)  // 16900

// fused tile: 8 rows x 32 cols; halo 10 x 34
#define HR3 10
#define HC3 34
#define NPXT3 (HR3 * HC3)   // 340
#define NCHUNK (NPXT3 * 8)  // 2720 16B-chunks

typedef __attribute__((ext_vector_type(8))) short bf16x8;
typedef __attribute__((ext_vector_type(4))) float f32x4;

static __device__ __forceinline__ short f2bf(float v) {
  union { float f; unsigned u; } a; a.f = v;
  unsigned r = a.u + 0x7fffu + ((a.u >> 16) & 1u);
  return (short)(r >> 16);
}
static __device__ __forceinline__ unsigned pkbf2(float lo, float hi) {
  __hip_bfloat162 pk = __float22bfloat162_rn(make_float2(lo, hi));
  union { __hip_bfloat162 h; unsigned u; } cv; cv.h = pk;
  return cv.u;
}
static __device__ __forceinline__ float bfu(unsigned u) {
  union { unsigned u; float f; } a; a.u = u; return a.f;
}

// ------------------------------------------------------------------
// prepack (blocks 0..143): Apack[p][64 m][64 n], A1pack[p][16 q][64 n];
// border-zero xT (blocks 144..151, one per batch)
__global__ __launch_bounds__(256) void k_pack(const float* __restrict__ wgt,
                                              const float* __restrict__ a1w1,
                                              short* __restrict__ Apack,
                                              short* __restrict__ A1pack,
                                              short* __restrict__ xT) {
  int bx = blockIdx.x;
  if (bx < 144) {
    int idx = bx * 256 + threadIdx.x;
    if (idx < 9 * 64 * 64) {
      int p = idx >> 12, m = (idx >> 6) & 63, n = idx & 63;
      Apack[idx] = f2bf(wgt[(m * 64 + n) * 9 + p]);
    }
    if (idx < 9 * 16 * 64) {
      int p = idx >> 10, q = (idx >> 6) & 15, n = idx & 63;
      A1pack[idx] = (q < 9) ? f2bf(a1w1[(q * 64 + n) * 9 + p]) : (short)0;
    }
  } else {
    int b = bx - 144;
    for (int c = threadIdx.x; c < 4128; c += 256) {
      int i = c >> 3, q = c & 7;
      int gpix;
      if (i < 130) gpix = i;
      else if (i < 260) gpix = 129 * 130 + (i - 130);
      else { int j = i - 260; gpix = (1 + (j >> 1)) * PH + ((j & 1) ? 129 : 0); }
      *(uint4*)(xT + ((size_t)b * PPIX + gpix) * 64 + q * 8) = make_uint4(0, 0, 0, 0);
    }
  }
}

// ------------------------------------------------------------------
// transpose x -> xT[b][padded pix][64ch] bf16
__global__ __launch_bounds__(256) void k_tr(const float* __restrict__ x,
                                            short* __restrict__ xT) {
  int b = blockIdx.y;
  int tid = threadIdx.x;
  int pix = (blockIdx.x << 8) + tid;
  const float* xb = x + (size_t)b * 64 * NPIX + pix;
  unsigned pk[32];
  #pragma unroll
  for (int cp = 0; cp < 32; cp++) {
    float v0 = xb[(size_t)(2 * cp) * NPIX];
    float v1 = xb[(size_t)(2 * cp + 1) * NPIX];
    pk[cp] = pkbf2(v0, v1);
  }
  int row = pix >> 7, col = pix & 127;
  short* dst = xT + ((size_t)b * PPIX + (size_t)(row + 1) * PH + (col + 1)) * 64;
  #pragma unroll
  for (int q = 0; q < 8; q++)
    *(uint4*)(dst + q * 8) =
        make_uint4(pk[4 * q], pk[4 * q + 1], pk[4 * q + 2], pk[4 * q + 3]);
}

// ------------------------------------------------------------------
// gpool from xT (bf16), deterministic two-stage reduce
__global__ __launch_bounds__(256) void k_gpool2(const short* __restrict__ xT,
                                                float* __restrict__ part) {
  int b = blockIdx.y, strip = blockIdx.x;
  int tid = threadIdx.x;
  int wid = tid >> 6, lane = tid & 63;
  int q = tid & 7, slot = tid >> 3;
  const short* xb = xT + (size_t)b * PPIX * 64;
  float s[8];
  #pragma unroll
  for (int k = 0; k < 8; k++) s[k] = 0.f;
  #pragma unroll 4
  for (int itr = 0; itr < 64; itr++) {
    int px = strip * 2048 + itr * 32 + slot;
    int r = px >> 7, c = px & 127;
    uint4 v = *(const uint4*)(xb + ((size_t)((r + 1) * PH + c + 1)) * 64 + q * 8);
    s[0] += bfu(v.x << 16); s[1] += bfu(v.x & 0xffff0000u);
    s[2] += bfu(v.y << 16); s[3] += bfu(v.y & 0xffff0000u);
    s[4] += bfu(v.z << 16); s[5] += bfu(v.z & 0xffff0000u);
    s[6] += bfu(v.w << 16); s[7] += bfu(v.w & 0xffff0000u);
  }
  #pragma unroll
  for (int o = 8; o < 64; o <<= 1)
    #pragma unroll
    for (int k = 0; k < 8; k++) s[k] += __shfl_down(s[k], o, 64);
  __shared__ float red[4][64];
  if (lane < 8) {
    #pragma unroll
    for (int k = 0; k < 8; k++) red[wid][lane * 8 + k] = s[k];
  }
  __syncthreads();
  if (tid < 64)
    part[((size_t)b * 8 + strip) * 64 + tid] =
        red[0][tid] + red[1][tid] + red[2][tid] + red[3][tid];
}

// ------------------------------------------------------------------
// dynamic bias from partials: one block (64 threads) per batch
__global__ __launch_bounds__(64) void k_bias(const float* __restrict__ part,
                                             const float* __restrict__ a3w1,
                                             const float* __restrict__ a3b1,
                                             const float* __restrict__ a3w2,
                                             const float* __restrict__ a3b2,
                                             float* __restrict__ bias) {
  int b = blockIdx.x;
  int t = threadIdx.x;
  __shared__ float gsh[64], h[64];
  float gs = 0.f;
  #pragma unroll
  for (int sIdx = 0; sIdx < 8; sIdx++) gs += part[((size_t)b * 8 + sIdx) * 64 + t];
  gsh[t] = gs * (1.0f / NPIX);
  __syncthreads();
  float s1 = a3b1[t];
  #pragma unroll
  for (int n = 0; n < 64; n++) s1 += a3w1[t * 64 + n] * gsh[n];
  h[t] = fmaxf(s1, 0.f);
  __syncthreads();
  float s2 = a3b2[t];
  #pragma unroll
  for (int c = 0; c < 64; c++) s2 += a3w2[t * 64 + c] * h[c];
  bias[b * 64 + t] = s2;
}

// ------------------------------------------------------------------
// fused v5: round-4 memory skeleton (2D grid, reg-staged LDS, 8-wave block)
// + b128 staging from xT + A-prefetch pipeline + shfl-MLP.
// block 512 thr = 8 waves; tile 8 rows x 32 cols; wave = 1 row x 32 px.
__global__ __launch_bounds__(512, 4) void k_fused(
    const short* __restrict__ xT, const short* __restrict__ Apack,
    const short* __restrict__ A1pack,
    const float* __restrict__ b1p, const float* __restrict__ w2p,
    const float* __restrict__ b2p, const float* __restrict__ w3p,
    const float* __restrict__ b3p,
    const float* __restrict__ bias, float* __restrict__ out) {
  __shared__ short xt[NPXT3 * 64];  // 43520 B

  int b = blockIdx.y;
  int ty = blockIdx.x >> 2, tx = blockIdx.x & 3;
  int row0 = ty * 8, col0 = tx * 32;

  int tid = threadIdx.x;
  int lane = tid & 63;
  int lp = lane & 15, kq = lane >> 4;
  int wr = tid >> 6;  // wave = tile row 0..7

  // ---- stage: 2720 b128 chunks; global reads linear, LDS-side XOR swizzle
  // LDS chunk (pix, qL) holds global chunk (pix, qL ^ (pix&7)).
  {
    const short* xTb = xT + (size_t)b * PPIX * 64;
    int base = row0 * PH + col0;
    bf16x8 v[5], vt;
    #pragma unroll
    for (int it = 0; it < 5; it++) {
      int c = tid + it * 512;
      int pix = c >> 3, q = c & 7;
      int r = pix / HC3, col = pix - r * HC3;
      v[it] = *(const bf16x8*)(xTb + ((size_t)(base + r * PH + col)) * 64 + q * 8);
    }
    bool tail = tid < (NCHUNK - 5 * 512);  // 160
    if (tail) {
      int c = tid + 2560;
      int pix = c >> 3, q = c & 7;
      int r = pix / HC3, col = pix - r * HC3;
      vt = *(const bf16x8*)(xTb + ((size_t)(base + r * PH + col)) * 64 + q * 8);
    }
    #pragma unroll
    for (int it = 0; it < 5; it++) {
      int c = tid + it * 512;
      int pix = c >> 3;
      *(bf16x8*)((char*)xt + ((c * 16) ^ ((pix & 7) << 4))) = v[it];
    }
    if (tail) {
      int c = tid + 2560;
      int pix = c >> 3;
      *(bf16x8*)((char*)xt + ((c * 16) ^ ((pix & 7) << 4))) = vt;
    }
  }
  __syncthreads();

  // ---- phase 1: conv1 MFMA (M=16 zero-padded), 1-deep A1 prefetch
  bf16x8 a1b_[2][2];
  #pragma unroll
  for (int ck = 0; ck < 2; ck++)
    a1b_[0][ck] = *(const bf16x8*)(A1pack + lp * 64 + ck * 32 + kq * 8);
  f32x4 acc1[2];
  acc1[0] = acc1[1] = (f32x4){0.f, 0.f, 0.f, 0.f};
  #pragma unroll
  for (int p = 0; p < 9; p++) {
    if (p < 8) {
      #pragma unroll
      for (int ck = 0; ck < 2; ck++)
        a1b_[(p + 1) & 1][ck] =
            *(const bf16x8*)(A1pack + ((p + 1) * 16 + lp) * 64 + ck * 32 + kq * 8);
    }
    const int di = p / 3, dj = p % 3;
    #pragma unroll
    for (int g = 0; g < 2; g++) {
      int pix = (wr + di) * HC3 + g * 16 + dj + lp;
      #pragma unroll
      for (int ck = 0; ck < 2; ck++) {
        int byteoff = (pix * 128 + ck * 64 + kq * 16) ^ ((pix & 7) << 4);
        bf16x8 bf = *(const bf16x8*)((const char*)xt + byteoff);
        acc1[g] = __builtin_amdgcn_mfma_f32_16x16x32_bf16(a1b_[p & 1][ck], bf, acc1[g], 0, 0, 0);
      }
    }
  }

  // ---- prefetch main-conv tap-0 A fragments (MLP below hides the latency)
  bf16x8 ab_[2][4][2];
  #pragma unroll
  for (int mt = 0; mt < 4; mt++)
    #pragma unroll
    for (int ck = 0; ck < 2; ck++)
      ab_[0][mt][ck] =
          *(const bf16x8*)(Apack + ((mt * 16 + lp) * 64 + ck * 32 + kq * 8));

  // ---- phase 2: shfl-MLP; every lane computes pixel (lane&15) of each group
  float aw[2][9];
  #pragma unroll
  for (int g = 0; g < 2; g++) {
    float a[9], t1[9], t2[9];
    #pragma unroll
    for (int q2 = 0; q2 < 9; q2++)
      a[q2] = __shfl(acc1[g][q2 & 3], (q2 >> 2) * 16 + lp, 64);
    #pragma unroll
    for (int q = 0; q < 9; q++) t1[q] = fmaxf(a[q] + b1p[q], 0.f);
    #pragma unroll
    for (int r = 0; r < 9; r++) {
      float s = b2p[r];
      #pragma unroll
      for (int q = 0; q < 9; q++) s += w2p[r * 9 + q] * t1[q];
      t2[r] = fmaxf(s, 0.f);
    }
    #pragma unroll
    for (int r = 0; r < 9; r++) {
      float s = b3p[r];
      #pragma unroll
      for (int q = 0; q < 9; q++) s += w3p[r * 9 + q] * t2[q];
      aw[g][r] = 1.f / (1.f + __expf(-s));
    }
  }

  // ---- phase 3: main conv, 1-deep A prefetch, scale-after-MFMA
  f32x4 acc[2][4];
  #pragma unroll
  for (int g = 0; g < 2; g++)
    #pragma unroll
    for (int mt = 0; mt < 4; mt++) acc[g][mt] = (f32x4){0.f, 0.f, 0.f, 0.f};

  #pragma unroll
  for (int p = 0; p < 9; p++) {
    if (p < 8) {
      #pragma unroll
      for (int mt = 0; mt < 4; mt++)
        #pragma unroll
        for (int ck = 0; ck < 2; ck++)
          ab_[(p + 1) & 1][mt][ck] = *(const bf16x8*)(
              Apack + (((p + 1) * 64 + mt * 16 + lp) * 64 + ck * 32 + kq * 8));
    }
    const int di = p / 3, dj = p % 3;
    bf16x8 fr[2][2];
    #pragma unroll
    for (int g = 0; g < 2; g++) {
      int pix = (wr + di) * HC3 + g * 16 + dj + lp;
      #pragma unroll
      for (int ck = 0; ck < 2; ck++) {
        int byteoff = (pix * 128 + ck * 64 + kq * 16) ^ ((pix & 7) << 4);
        fr[g][ck] = *(const bf16x8*)((const char*)xt + byteoff);
      }
    }
    #pragma unroll
    for (int mt = 0; mt < 4; mt++) {
      #pragma unroll
      for (int g = 0; g < 2; g++) {
        f32x4 tmp = (f32x4){0.f, 0.f, 0.f, 0.f};
        tmp = __builtin_amdgcn_mfma_f32_16x16x32_bf16(ab_[p & 1][mt][0], fr[g][0], tmp, 0, 0, 0);
        tmp = __builtin_amdgcn_mfma_f32_16x16x32_bf16(ab_[p & 1][mt][1], fr[g][1], tmp, 0, 0, 0);
        float awp = aw[g][p];
        #pragma unroll
        for (int r = 0; r < 4; r++) acc[g][mt][r] += awp * tmp[r];
      }
    }
  }

  // ---- epilogue: bias + stores, both 64B halves of each line adjacent
  int i = row0 + wr;
  #pragma unroll
  for (int mt = 0; mt < 4; mt++) {
    f32x4 bv = *(const f32x4*)(bias + b * 64 + mt * 16 + kq * 4);
    #pragma unroll
    for (int r = 0; r < 4; r++) {
      int m = mt * 16 + kq * 4 + r;
      float* o = out + (((size_t)b * 64 + m) * HW + i) * HW;
      float v0 = acc[0][mt][r] + bv[r];
      float v1 = acc[1][mt][r] + bv[r];
      o[col0 + lp] = v0;
      o[col0 + 16 + lp] = v1;
    }
  }
}

// ------------------------------------------------------------------
extern "C" void kernel_launch(void* const* d_in, const int* in_sizes, int n_in,
                              void* d_out, int out_size, void* d_ws, size_t ws_size,
                              hipStream_t stream) {
  const float* x    = (const float*)d_in[0];
  const float* a1w1 = (const float*)d_in[1];
  const float* a1b1 = (const float*)d_in[2];
  const float* a1w2 = (const float*)d_in[3];
  const float* a1b2 = (const float*)d_in[4];
  const float* a1w3 = (const float*)d_in[5];
  const float* a1b3 = (const float*)d_in[6];
  const float* a3w1 = (const float*)d_in[7];
  const float* a3b1 = (const float*)d_in[8];
  const float* a3w2 = (const float*)d_in[9];
  const float* a3b2 = (const float*)d_in[10];
  const float* wgt  = (const float*)d_in[11];
  float* out = (float*)d_out;

  const size_t xT_sh = (size_t)NB * PPIX * 64;   // shorts
  short* xT     = (short*)d_ws;
  float* part   = (float*)(xT + xT_sh);          // NB*8*64 floats
  float* bias   = part + NB * 8 * 64;            // 512
  short* Apack  = (short*)(bias + NB * 64);      // 9*64*64
  short* A1pack = Apack + 9 * 64 * 64;           // 9*16*64

  k_pack<<<dim3(152), dim3(256), 0, stream>>>(wgt, a1w1, Apack, A1pack, xT);
  k_tr<<<dim3(64, NB), dim3(256), 0, stream>>>(x, xT);
  k_gpool2<<<dim3(8, NB), dim3(256), 0, stream>>>(xT, part);
  k_bias<<<dim3(NB), dim3(64), 0, stream>>>(part, a3w1, a3b1, a3w2, a3b2, bias);
  k_fused<<<dim3(64, NB), dim3(512), 0, stream>>>(xT, Apack, A1pack,
                                                  a1b1, a1w2, a1b2, a1w3, a1b3,
                                                  bias, out);
}

// Round 8
// 85.005 us; speedup vs baseline: 1.9111x; 1.9111x over previous
//
#include <hip/hip_runtime.h>
#include <hip/hip_bf16.h>
#include <math.h>

#define HW 128
#define NPIX (HW * HW)
#define NB 8
#define PH 130
#define PPIX (PH * PH)  // 16900

// fused tile: 8 rows x 32 cols; halo 10 x 34 (round-4 proven geometry)
#define TROWS 8
#define HR2 10
#define HC2 34
#define NPXT (HR2 * HC2)  // 340
#define ABST 20           // ab pixel stride (floats)

typedef __attribute__((ext_vector_type(8))) short bf16x8;
typedef __attribute__((ext_vector_type(4))) float f32x4;

static __device__ __forceinline__ short f2bf(float v) {
  union { float f; unsigned u; } a; a.f = v;
  unsigned r = a.u + 0x7fffu + ((a.u >> 16) & 1u);
  return (short)(r >> 16);
}
static __device__ __forceinline__ float bfbits2f(unsigned u) {
  union { unsigned u; float f; } a; a.u = u; return a.f;
}
static __device__ __forceinline__ unsigned pkbf2(float lo, float hi) {
  __hip_bfloat162 pk = __float22bfloat162_rn(make_float2(lo, hi));
  union { __hip_bfloat162 h; unsigned u; } cv; cv.h = pk;
  return cv.u;
}

// ------------------------------------------------------------------
// prepack (blocks 0..143): Apack[p][64 m][64 n], A1pack[p][16 q][64 n];
// border-zero xT (blocks 144..151, one per batch)
__global__ __launch_bounds__(256) void k_pack(const float* __restrict__ wgt,
                                              const float* __restrict__ a1w1,
                                              short* __restrict__ Apack,
                                              short* __restrict__ A1pack,
                                              short* __restrict__ xT) {
  int bx = blockIdx.x;
  if (bx < 144) {
    int idx = bx * 256 + threadIdx.x;
    if (idx < 9 * 64 * 64) {
      int p = idx >> 12, m = (idx >> 6) & 63, n = idx & 63;
      Apack[idx] = f2bf(wgt[(m * 64 + n) * 9 + p]);
    }
    if (idx < 9 * 16 * 64) {
      int p = idx >> 10, q = (idx >> 6) & 15, n = idx & 63;
      A1pack[idx] = (q < 9) ? f2bf(a1w1[(q * 64 + n) * 9 + p]) : (short)0;
    }
  } else {
    int b = bx - 144;
    for (int c = threadIdx.x; c < 4128; c += 256) {
      int i = c >> 3, q = c & 7;
      int gpix;
      if (i < 130) gpix = i;
      else if (i < 260) gpix = 129 * 130 + (i - 130);
      else { int j = i - 260; gpix = (1 + (j >> 1)) * PH + ((j & 1) ? 129 : 0); }
      *(uint4*)(xT + ((size_t)b * PPIX + gpix) * 64 + q * 8) = make_uint4(0, 0, 0, 0);
    }
  }
}

// ------------------------------------------------------------------
// transpose x -> xT[b][padded pix][64ch] bf16 (pure copy)
__global__ __launch_bounds__(256) void k_tr(const float* __restrict__ x,
                                            short* __restrict__ xT) {
  int b = blockIdx.y;
  int tid = threadIdx.x;
  int pix = (blockIdx.x << 8) + tid;
  const float* xb = x + (size_t)b * 64 * NPIX + pix;
  unsigned pk[32];
  #pragma unroll
  for (int cp = 0; cp < 32; cp++) {
    float v0 = xb[(size_t)(2 * cp) * NPIX];
    float v1 = xb[(size_t)(2 * cp + 1) * NPIX];
    pk[cp] = pkbf2(v0, v1);
  }
  int row = pix >> 7, col = pix & 127;
  short* dst = xT + ((size_t)b * PPIX + (size_t)(row + 1) * PH + (col + 1)) * 64;
  #pragma unroll
  for (int q = 0; q < 8; q++)
    *(uint4*)(dst + q * 8) =
        make_uint4(pk[4 * q], pk[4 * q + 1], pk[4 * q + 2], pk[4 * q + 3]);
}

// ------------------------------------------------------------------
// gpool from xT (bf16), deterministic two-stage reduce
__global__ __launch_bounds__(256) void k_gpool2(const short* __restrict__ xT,
                                                float* __restrict__ part) {
  int b = blockIdx.y, strip = blockIdx.x;
  int tid = threadIdx.x;
  int wid = tid >> 6, lane = tid & 63;
  int q = tid & 7, slot = tid >> 3;
  const short* xb = xT + (size_t)b * PPIX * 64;
  float s[8];
  #pragma unroll
  for (int k = 0; k < 8; k++) s[k] = 0.f;
  #pragma unroll 4
  for (int itr = 0; itr < 64; itr++) {
    int px = strip * 2048 + itr * 32 + slot;
    int r = px >> 7, c = px & 127;
    uint4 v = *(const uint4*)(xb + ((size_t)((r + 1) * PH + c + 1)) * 64 + q * 8);
    s[0] += bfbits2f(v.x << 16); s[1] += bfbits2f(v.x & 0xffff0000u);
    s[2] += bfbits2f(v.y << 16); s[3] += bfbits2f(v.y & 0xffff0000u);
    s[4] += bfbits2f(v.z << 16); s[5] += bfbits2f(v.z & 0xffff0000u);
    s[6] += bfbits2f(v.w << 16); s[7] += bfbits2f(v.w & 0xffff0000u);
  }
  #pragma unroll
  for (int o = 8; o < 64; o <<= 1)
    #pragma unroll
    for (int k = 0; k < 8; k++) s[k] += __shfl_down(s[k], o, 64);
  __shared__ float red[4][64];
  if (lane < 8) {
    #pragma unroll
    for (int k = 0; k < 8; k++) red[wid][lane * 8 + k] = s[k];
  }
  __syncthreads();
  if (tid < 64)
    part[((size_t)b * 8 + strip) * 64 + tid] =
        red[0][tid] + red[1][tid] + red[2][tid] + red[3][tid];
}

// ------------------------------------------------------------------
// dynamic bias from partials: one block (64 threads) per batch
__global__ __launch_bounds__(64) void k_bias(const float* __restrict__ part,
                                             const float* __restrict__ a3w1,
                                             const float* __restrict__ a3b1,
                                             const float* __restrict__ a3w2,
                                             const float* __restrict__ a3b2,
                                             float* __restrict__ bias) {
  int b = blockIdx.x;
  int t = threadIdx.x;
  __shared__ float gsh[64], h[64];
  float gs = 0.f;
  #pragma unroll
  for (int sIdx = 0; sIdx < 8; sIdx++) gs += part[((size_t)b * 8 + sIdx) * 64 + t];
  gsh[t] = gs * (1.0f / NPIX);
  __syncthreads();
  float s1 = a3b1[t];
  #pragma unroll
  for (int n = 0; n < 64; n++) s1 += a3w1[t * 64 + n] * gsh[n];
  h[t] = fmaxf(s1, 0.f);
  __syncthreads();
  float s2 = a3b2[t];
  #pragma unroll
  for (int c = 0; c < 64; c++) s2 += a3w2[t * 64 + c] * h[c];
  bias[b * 64 + t] = s2;
}

// ------------------------------------------------------------------
// fused: ROUND-4 VERBATIM (proven 53 us, WRITE=32768KB exactly, FETCH=11.4MB).
// block 512 thr = 8 waves; tile 8 rows x 32 cols; wave = 1 row x 32 cols.
// Fits the 128-VGPR budget of __launch_bounds__(512,4) -- no spill.
__global__ __launch_bounds__(512, 4) void k_fused(
    const short* __restrict__ xT, const short* __restrict__ Apack,
    const short* __restrict__ A1pack,
    const float* __restrict__ b1p, const float* __restrict__ w2p,
    const float* __restrict__ b2p, const float* __restrict__ w3p,
    const float* __restrict__ b3p,
    const float* __restrict__ bias, float* __restrict__ out) {
  __shared__ short xt[NPXT * 64];        // [pix][64 ch] bf16, byte^((pix&7)<<4)
  __shared__ float ab[TROWS][32][ABST];  // a-values then atw, per wave

  int b = blockIdx.y;
  int ty = blockIdx.x >> 2, tx = blockIdx.x & 3;
  int tid = threadIdx.x;
  int wid = tid >> 6, lane = tid & 63;
  int lp = lane & 15, kq = lane >> 4;
  int row0 = ty * TROWS, col0 = tx * 32;

  // ---- stage from xT: interleaved b128 copy, swizzled LDS writes
  {
    const short* xTb = xT + (size_t)b * PPIX * 64;
    int base = row0 * PH + col0;
    for (int c = tid; c < NPXT * 8; c += 512) {
      int pix = c >> 3;
      int r = pix / HC2;
      int col = pix - r * HC2;
      bf16x8 v = *(const bf16x8*)(xTb + ((size_t)(base + r * PH + col)) * 64 + (c & 7) * 8);
      int dst = (c * 16) ^ ((pix & 7) << 4);
      *(bf16x8*)((char*)xt + dst) = v;
    }
  }
  __syncthreads();

  // ---- phase 1: conv1 via MFMA (M=16 padded, K=576)
  f32x4 acc1[2];
  #pragma unroll
  for (int g = 0; g < 2; g++) acc1[g] = (f32x4){0.f, 0.f, 0.f, 0.f};

  #pragma unroll
  for (int p = 0; p < 9; p++) {
    const int di = p / 3, dj = p % 3;
    int rt = wid + di;
    #pragma unroll
    for (int ck = 0; ck < 2; ck++) {
      bf16x8 af1 = *(const bf16x8*)(A1pack + (p * 16 + lp) * 64 + ck * 32 + kq * 8);
      #pragma unroll
      for (int g = 0; g < 2; g++) {
        int pix = rt * HC2 + g * 16 + lp + dj;
        int byteoff = (pix * 128 + ck * 64 + kq * 16) ^ ((pix & 7) << 4);
        bf16x8 bf = *(const bf16x8*)((const char*)xt + byteoff);
        acc1[g] = __builtin_amdgcn_mfma_f32_16x16x32_bf16(af1, bf, acc1[g], 0, 0, 0);
      }
    }
  }
  #pragma unroll
  for (int g = 0; g < 2; g++)
    *(f32x4*)&ab[wid][g * 16 + lp][kq * 4] = acc1[g];
  __syncthreads();

  // ---- phase 2: per-pixel MLP -> atw (in place in ab)
  if (lane < 32) {
    float a[9], t1[9], t2[9];
    #pragma unroll
    for (int q = 0; q < 9; q++) a[q] = ab[wid][lane][q];
    #pragma unroll
    for (int q = 0; q < 9; q++) t1[q] = fmaxf(a[q] + b1p[q], 0.f);
    #pragma unroll
    for (int r = 0; r < 9; r++) {
      float s = b2p[r];
      #pragma unroll
      for (int q = 0; q < 9; q++) s += w2p[r * 9 + q] * t1[q];
      t2[r] = fmaxf(s, 0.f);
    }
    #pragma unroll
    for (int r = 0; r < 9; r++) {
      float s = b3p[r];
      #pragma unroll
      for (int q = 0; q < 9; q++) s += w3p[r * 9 + q] * t2[q];
      ab[wid][lane][r] = 1.f / (1.f + __expf(-s));
    }
  }
  __syncthreads();

  // ---- phase 3: main conv via MFMA with atw-scaled fragments
  f32x4 acc[2][4];
  #pragma unroll
  for (int g = 0; g < 2; g++)
    #pragma unroll
    for (int mt = 0; mt < 4; mt++) acc[g][mt] = (f32x4){0.f, 0.f, 0.f, 0.f};

  f32x4 awA[2], awB[2];
  float awC[2];
  #pragma unroll
  for (int g = 0; g < 2; g++) {
    const float* abp = &ab[wid][g * 16 + lp][0];
    awA[g] = *(const f32x4*)abp;
    awB[g] = *(const f32x4*)(abp + 4);
    awC[g] = abp[8];
  }

  #pragma unroll
  for (int p = 0; p < 9; p++) {
    const int di = p / 3, dj = p % 3;
    int rt = wid + di;
    // A fragments first (global; L1-resident after first wave)
    bf16x8 af[2][4];
    #pragma unroll
    for (int ck = 0; ck < 2; ck++)
      #pragma unroll
      for (int mt = 0; mt < 4; mt++)
        af[ck][mt] = *(const bf16x8*)(Apack + ((p * 64 + mt * 16 + lp) * 64 + ck * 32 + kq * 8));

    bf16x8 frag[2][2];
    #pragma unroll
    for (int g = 0; g < 2; g++) {
      float awv = (p < 4) ? awA[g][p] : (p < 8) ? awB[g][p - 4] : awC[g];
      int pix = rt * HC2 + g * 16 + lp + dj;
      #pragma unroll
      for (int ck = 0; ck < 2; ck++) {
        int byteoff = (pix * 128 + ck * 64 + kq * 16) ^ ((pix & 7) << 4);
        union { bf16x8 v; unsigned u[4]; } in, op;
        in.v = *(const bf16x8*)((const char*)xt + byteoff);
        #pragma unroll
        for (int d = 0; d < 4; d++) {
          float lo = bfbits2f(in.u[d] << 16) * awv;
          float hi = bfbits2f(in.u[d] & 0xffff0000u) * awv;
          op.u[d] = pkbf2(lo, hi);
        }
        frag[g][ck] = op.v;
      }
    }
    #pragma unroll
    for (int mt = 0; mt < 4; mt++)
      #pragma unroll
      for (int ck = 0; ck < 2; ck++)
        #pragma unroll
        for (int g = 0; g < 2; g++)
          acc[g][mt] = __builtin_amdgcn_mfma_f32_16x16x32_bf16(af[ck][mt], frag[g][ck], acc[g][mt], 0, 0, 0);
  }

  // ---- epilogue
  int i = row0 + wid;
  #pragma unroll
  for (int mt = 0; mt < 4; mt++) {
    #pragma unroll
    for (int r = 0; r < 4; r++) {
      int m = mt * 16 + kq * 4 + r;
      float bv = bias[b * 64 + m];
      #pragma unroll
      for (int g = 0; g < 2; g++) {
        int j = col0 + g * 16 + lp;
        out[(((size_t)b * 64 + m) * HW + i) * HW + j] = acc[g][mt][r] + bv;
      }
    }
  }
}

// ------------------------------------------------------------------
extern "C" void kernel_launch(void* const* d_in, const int* in_sizes, int n_in,
                              void* d_out, int out_size, void* d_ws, size_t ws_size,
                              hipStream_t stream) {
  const float* x    = (const float*)d_in[0];
  const float* a1w1 = (const float*)d_in[1];
  const float* a1b1 = (const float*)d_in[2];
  const float* a1w2 = (const float*)d_in[3];
  const float* a1b2 = (const float*)d_in[4];
  const float* a1w3 = (const float*)d_in[5];
  const float* a1b3 = (const float*)d_in[6];
  const float* a3w1 = (const float*)d_in[7];
  const float* a3b1 = (const float*)d_in[8];
  const float* a3w2 = (const float*)d_in[9];
  const float* a3b2 = (const float*)d_in[10];
  const float* wgt  = (const float*)d_in[11];
  float* out = (float*)d_out;

  const size_t xT_sh = (size_t)NB * PPIX * 64;   // shorts
  short* xT     = (short*)d_ws;
  float* part   = (float*)(xT + xT_sh);          // NB*8*64 floats
  float* bias   = part + NB * 8 * 64;            // 512
  short* Apack  = (short*)(bias + NB * 64);      // 9*64*64
  short* A1pack = Apack + 9 * 64 * 64;           // 9*16*64

  k_pack<<<dim3(152), dim3(256), 0, stream>>>(wgt, a1w1, Apack, A1pack, xT);
  k_tr<<<dim3(64, NB), dim3(256), 0, stream>>>(x, xT);
  k_gpool2<<<dim3(8, NB), dim3(256), 0, stream>>>(xT, part);
  k_bias<<<dim3(NB), dim3(64), 0, stream>>>(part, a3w1, a3b1, a3w2, a3b2, bias);
  k_fused<<<dim3(64, NB), dim3(512), 0, stream>>>(xT, Apack, A1pack,
                                                  a1b1, a1w2, a1b2, a1w3, a1b3,
                                                  bias, out);
}